// Round 2
// baseline (216.173 us; speedup 1.0000x reference)
//
#include <hip/hip_runtime.h>
#include <hip/hip_bf16.h>
#include <stdint.h>

// GCN 5-layer, N=100000, E=600000. Bucket-CSR, norm folded into epilogues.
// Round-13: W2 commuted past the layer-2 aggregation so the gathered tensor
// is G = dis*relu(L1) >= 0, stored as per-row-scaled uint8 (step=rowmax/255,
// ~8 sig bits vs fp8's 4 -> R1's accuracy failure mode avoided). Dominant
// gather stream halves: 154 MB bf16 -> 77 MB u8 (+0.4 MB scales). k_aggu8
// does both W2 and W3 MFMAs (net MFMA count unchanged). A/C paths stay at
// the proven bf16 baseline. absmax predicted ~7.8e-4 (< 9.7e-4).

#define NB 256
#define CAP 64

typedef __attribute__((ext_vector_type(8))) short bf16x8;
typedef __attribute__((ext_vector_type(4))) float f32x4;

static __host__ __device__ inline int ceil_div(int a, int b) { return (a + b - 1) / b; }

__device__ inline ushort f32_to_bf16(float x) {   // RNE
    uint32_t u = __float_as_uint(x);
    uint32_t r = (u + 0x7fffu + ((u >> 16) & 1u)) >> 16;
    return (ushort)r;
}
__device__ inline float bf16_lo(uint32_t u) { return __uint_as_float(u << 16); }
__device__ inline float bf16_hi(uint32_t u) { return __uint_as_float(u & 0xffff0000u); }

// ---------------- init: zero cursor + pack weights ----------------

template <int K, int F>
__device__ inline void pack_one(const float* __restrict__ W, ushort* __restrict__ Wp, int id) {
    constexpr int KS = K / 32;
    int j = id & 7;
    int lane = (id >> 3) & 63;
    int ts = id >> 9;
    int s = ts % KS;
    int t = ts / KS;
    int k = s * 32 + ((lane >> 4) << 3) + j;
    int f = t * 16 + (lane & 15);
    Wp[id] = f32_to_bf16(W[k * F + f]);
}

__global__ void k_init(int* __restrict__ cursor, int n, int zero_blocks,
                       const float* __restrict__ W2, const float* __restrict__ W3,
                       const float* __restrict__ W4, ushort* __restrict__ Wp2,
                       ushort* __restrict__ Wp3, ushort* __restrict__ Wp4) {
    int b = blockIdx.x;
    if (b < zero_blocks) {
        int i = b * NB + threadIdx.x;
        if (i < n) cursor[i] = 0;
    } else {
        int id = (b - zero_blocks) * NB + threadIdx.x;
        if (id < 16384) pack_one<128, 128>(W2, Wp2, id);
        else if (id < 24576) pack_one<128, 64>(W3, Wp3, id - 16384);
        else if (id < 28672) pack_one<64, 64>(W4, Wp4, id - 24576);
    }
}

// ---------------- bucket CSR fill: x8 unrolled for atomic MLP ----------------

__global__ void k_fillb(const int* __restrict__ row, const int* __restrict__ col, int e,
                        int* __restrict__ cursor, int* __restrict__ bucket) {
    int T = (e + 7) >> 3;
    int t = blockIdx.x * NB + threadIdx.x;
    int i[8];
#pragma unroll
    for (int k = 0; k < 8; ++k) i[k] = t + k * T;
    if (i[7] < e) {
        int c[8], r[8], s[8];
#pragma unroll
        for (int k = 0; k < 8; ++k) { c[k] = col[i[k]]; r[k] = row[i[k]]; }
#pragma unroll
        for (int k = 0; k < 8; ++k) s[k] = atomicAdd(&cursor[c[k]], 1);
#pragma unroll
        for (int k = 0; k < 8; ++k) bucket[(size_t)c[k] * CAP + s[k]] = r[k];
    } else {
#pragma unroll
        for (int k = 0; k < 8; ++k) {
            if (i[k] < e) {
                int c = col[i[k]], r = row[i[k]];
                int s = atomicAdd(&cursor[c], 1);
                bucket[(size_t)c * CAP + s] = r;
            }
        }
    }
}

// dis/xs + bucket padding to x8 with dummy index n + zero rows for pad gathers
__global__ void k_dis(const int* __restrict__ cnt, const float* __restrict__ x,
                      float* __restrict__ dis, float4* __restrict__ xs4,
                      int* __restrict__ bucket, uint8_t* __restrict__ G,
                      float* __restrict__ sG, ushort* __restrict__ A,
                      ushort* __restrict__ C, float* __restrict__ zbuf, int n) {
    int i = blockIdx.x * NB + threadIdx.x;
    if (i < n) {
        int deg = cnt[i];
        float d = rsqrtf((float)(deg + 1));
        dis[i] = d;
        xs4[i] = make_float4(d * x[3 * i], d * x[3 * i + 1], d * x[3 * i + 2], 0.f);
        int dp = (deg + 7) & ~7;
        for (int e = deg; e < dp; ++e) bucket[(size_t)i * CAP + e] = n;
    } else if (i == n) {
        xs4[n] = make_float4(0.f, 0.f, 0.f, 0.f);
        zbuf[n] = 0.f;
        sG[n] = 0.f;
        uint4 z = make_uint4(0, 0, 0, 0);
        uint4* Gn = (uint4*)(G + (size_t)n * 128);   // 128 B
        uint4* An = (uint4*)(A + (size_t)n * 64);    // 128 B
        uint4* Cn = (uint4*)(C + (size_t)n * 64);    // 128 B
#pragma unroll
        for (int k = 0; k < 8; ++k) { Gn[k] = z; An[k] = z; Cn[k] = z; }
    }
}

// ---------------- layer1: agg3(x) -> H1 (f32) -> G = dis*H1 as u8/rowscale ----------------

__global__ __launch_bounds__(256) void k_l1q(const float4* __restrict__ xs4,
                                             const int* __restrict__ cnt,
                                             const int* __restrict__ bucket,
                                             const float* __restrict__ dis,
                                             const float* __restrict__ W1,
                                             const float* __restrict__ b1,
                                             uint8_t* __restrict__ G,
                                             float* __restrict__ sG, int n) {
    __shared__ float w[512];          // W1 (384) + b1 (128)
    __shared__ float s_a[64][4];
    for (int t = threadIdx.x; t < 512; t += 256)
        w[t] = (t < 384) ? W1[t] : b1[t - 384];

    int node0 = blockIdx.x * 64;
    int local = threadIdx.x >> 2;
    int sub = threadIdx.x & 3;
    int i = node0 + local;
    float a0 = 0.f, a1 = 0.f, a2 = 0.f;
    if (i < n) {
        if (sub == 0) {
            float4 self = xs4[i];
            a0 = self.x; a1 = self.y; a2 = self.z;
        }
        int deg = cnt[i];
        const int* bk = bucket + (size_t)i * CAP;
        for (int e = sub; e < deg; e += 4) {
            float4 v = xs4[bk[e]];
            a0 += v.x; a1 += v.y; a2 += v.z;
        }
    }
    a0 += __shfl_xor(a0, 1, 64); a1 += __shfl_xor(a1, 1, 64); a2 += __shfl_xor(a2, 1, 64);
    a0 += __shfl_xor(a0, 2, 64); a1 += __shfl_xor(a1, 2, 64); a2 += __shfl_xor(a2, 2, 64);
    if (sub == 0) {
        float d = (i < n) ? dis[i] : 0.f;
        s_a[local][0] = a0 * d;
        s_a[local][1] = a1 * d;
        s_a[local][2] = a2 * d;
        s_a[local][3] = d;
    }
    __syncthreads();

    // expand: one wave per node per iter; 2 feats/lane; quantize row to u8
#pragma unroll
    for (int it = 0; it < 16; ++it) {
        int id = it * 256 + threadIdx.x;
        int lc = id >> 6;                 // node local index (wave-aligned)
        int f = (id & 63) * 2;
        float h0 = s_a[lc][0], h1 = s_a[lc][1], h2 = s_a[lc][2], d = s_a[lc][3];
        float v0 = fmaxf(h0 * w[f] + h1 * w[128 + f] + h2 * w[256 + f] + w[384 + f], 0.f) * d;
        float v1 = fmaxf(h0 * w[f + 1] + h1 * w[128 + f + 1] + h2 * w[256 + f + 1] + w[384 + f + 1], 0.f) * d;
        float m = fmaxf(v0, v1);
#pragma unroll
        for (int off = 1; off < 64; off <<= 1) m = fmaxf(m, __shfl_xor(m, off, 64));
        float inv = (m > 0.f) ? 255.f / m : 0.f;
        uint32_t u0 = (uint32_t)__float2int_rn(v0 * inv);
        uint32_t u1 = (uint32_t)__float2int_rn(v1 * inv);
        int node = node0 + lc;
        if (node < n) {
            *(ushort*)&G[(size_t)node * 128 + f] = (ushort)(u0 | (u1 << 8));
            if ((threadIdx.x & 63) == 0) sG[node] = m * (1.f / 255.f);
        }
    }
}

// ---------------- layer2: u8 agg(G) -> @W2 +b2 relu -> @W3 -> A ----------------

__device__ inline void accum_u8(float (&a)[8], uint2 v, float s) {
    uint32_t x = v.x, y = v.y;
    a[0] = fmaf((float)(x & 0xffu), s, a[0]);
    a[1] = fmaf((float)((x >> 8) & 0xffu), s, a[1]);
    a[2] = fmaf((float)((x >> 16) & 0xffu), s, a[2]);
    a[3] = fmaf((float)(x >> 24), s, a[3]);
    a[4] = fmaf((float)(y & 0xffu), s, a[4]);
    a[5] = fmaf((float)((y >> 8) & 0xffu), s, a[5]);
    a[6] = fmaf((float)((y >> 16) & 0xffu), s, a[6]);
    a[7] = fmaf((float)(y >> 24), s, a[7]);
}

__global__ __launch_bounds__(256) void k_aggu8(const uint8_t* __restrict__ G,
                                               const float* __restrict__ sG,
                                               const float* __restrict__ b2,
                                               const int* __restrict__ cnt,
                                               const int* __restrict__ bucket,
                                               const float* __restrict__ dis,
                                               const ushort* __restrict__ Wp2,
                                               const ushort* __restrict__ Wp3,
                                               ushort* __restrict__ A, int n) {
    __shared__ ushort tile[64][136];   // 128 + 8 pad; reused in place for both MFMAs
    int node0 = blockIdx.x * 64;
    const uint2* Gq = (const uint2*)G;

    {   // stage 1: u8 gather-sum, 16 lanes/node, 8-deep
        int l = threadIdx.x & 15;
        int g = threadIdx.x >> 4;
#pragma unroll
        for (int pass = 0; pass < 4; ++pass) {
            int local = pass * 16 + g;
            int i = node0 + local;
            if (i < n) {
                float a[8] = {0.f, 0.f, 0.f, 0.f, 0.f, 0.f, 0.f, 0.f};
                int degp = (cnt[i] + 7) & ~7;
                const int* bk = bucket + (size_t)i * CAP;
                accum_u8(a, Gq[(size_t)i * 16 + l], sG[i]);   // self
                for (int e = 0; e < degp; e += 8) {
                    int4 ja = *(const int4*)(bk + e);
                    int4 jb = *(const int4*)(bk + e + 4);
                    uint2 v0 = Gq[(size_t)ja.x * 16 + l]; float s0 = sG[ja.x];
                    uint2 v1 = Gq[(size_t)ja.y * 16 + l]; float s1 = sG[ja.y];
                    uint2 v2 = Gq[(size_t)ja.z * 16 + l]; float s2 = sG[ja.z];
                    uint2 v3 = Gq[(size_t)ja.w * 16 + l]; float s3 = sG[ja.w];
                    uint2 v4 = Gq[(size_t)jb.x * 16 + l]; float s4 = sG[jb.x];
                    uint2 v5 = Gq[(size_t)jb.y * 16 + l]; float s5 = sG[jb.y];
                    uint2 v6 = Gq[(size_t)jb.z * 16 + l]; float s6 = sG[jb.z];
                    uint2 v7 = Gq[(size_t)jb.w * 16 + l]; float s7 = sG[jb.w];
                    accum_u8(a, v0, s0);
                    accum_u8(a, v1, s1);
                    accum_u8(a, v2, s2);
                    accum_u8(a, v3, s3);
                    accum_u8(a, v4, s4);
                    accum_u8(a, v5, s5);
                    accum_u8(a, v6, s6);
                    accum_u8(a, v7, s7);
                }
                float d = dis[i];
                uint4 o;
                o.x = ((uint32_t)f32_to_bf16(d * a[1]) << 16) | (uint32_t)f32_to_bf16(d * a[0]);
                o.y = ((uint32_t)f32_to_bf16(d * a[3]) << 16) | (uint32_t)f32_to_bf16(d * a[2]);
                o.z = ((uint32_t)f32_to_bf16(d * a[5]) << 16) | (uint32_t)f32_to_bf16(d * a[4]);
                o.w = ((uint32_t)f32_to_bf16(d * a[7]) << 16) | (uint32_t)f32_to_bf16(d * a[6]);
                *(uint4*)&tile[local][l * 8] = o;
            }
        }
    }
    __syncthreads();

    int wid = threadIdx.x >> 6;
    int lane = threadIdx.x & 63;
    int m = lane & 15;
    int quad = lane >> 4;
    int tbase = wid * 16;

    // MFMA1: tile @ Wp2, +b2, relu -> tile (own 16-row band only: no barrier)
    bf16x8 af[4];
#pragma unroll
    for (int s = 0; s < 4; ++s)
        af[s] = *(const bf16x8*)&tile[tbase + m][s * 32 + quad * 8];
    float b2v[8];
#pragma unroll
    for (int t = 0; t < 8; ++t) b2v[t] = b2[t * 16 + m];
    const bf16x8* bp2 = (const bf16x8*)Wp2;
#pragma unroll
    for (int t = 0; t < 8; ++t) {
        f32x4 acc = {0.f, 0.f, 0.f, 0.f};
#pragma unroll
        for (int s = 0; s < 4; ++s)
            acc = __builtin_amdgcn_mfma_f32_16x16x32_bf16(af[s], bp2[(t * 4 + s) * 64 + lane], acc, 0, 0, 0);
#pragma unroll
        for (int r = 0; r < 4; ++r)
            tile[tbase + quad * 4 + r][t * 16 + m] = f32_to_bf16(fmaxf(acc[r] + b2v[t], 0.f));
    }

    // MFMA2: tile @ Wp3, * dis -> A
    bf16x8 af2[4];
#pragma unroll
    for (int s = 0; s < 4; ++s)
        af2[s] = *(const bf16x8*)&tile[tbase + m][s * 32 + quad * 8];
    float dsc[4];
#pragma unroll
    for (int r = 0; r < 4; ++r) {
        int node = node0 + tbase + quad * 4 + r;
        dsc[r] = (node < n) ? dis[node] : 0.f;
    }
    const bf16x8* bp3 = (const bf16x8*)Wp3;
#pragma unroll
    for (int t = 0; t < 4; ++t) {
        f32x4 acc = {0.f, 0.f, 0.f, 0.f};
#pragma unroll
        for (int s = 0; s < 4; ++s)
            acc = __builtin_amdgcn_mfma_f32_16x16x32_bf16(af2[s], bp3[(t * 4 + s) * 64 + lane], acc, 0, 0, 0);
        int feat = t * 16 + m;
#pragma unroll
        for (int r = 0; r < 4; ++r) {
            int node = node0 + tbase + quad * 4 + r;
            if (node < n) A[(size_t)node * 64 + feat] = f32_to_bf16(acc[r] * dsc[r]);
        }
    }
}

// ---------------- bf16 aggregation primitives (baseline) ----------------

__device__ inline void add8(float (&a)[8], uint4 v) {
    a[0] += bf16_lo(v.x);
    a[1] += bf16_hi(v.x);
    a[2] += bf16_lo(v.y);
    a[3] += bf16_hi(v.y);
    a[4] += bf16_lo(v.z);
    a[5] += bf16_hi(v.z);
    a[6] += bf16_lo(v.w);
    a[7] += bf16_hi(v.w);
}

// L lanes per node; degp multiple of 4 (padded with zero-row index n).
template <int L>
__device__ inline void agg_sum(float (&a)[8], const uint4* __restrict__ Zq,
                               const int* __restrict__ bk, int degp, int l, int i) {
    add8(a, Zq[(size_t)i * L + l]);   // self
    for (int e = 0; e < degp; e += 4) {
        int4 j4 = *(const int4*)(bk + e);
        uint4 v0 = Zq[(size_t)j4.x * L + l];
        uint4 v1 = Zq[(size_t)j4.y * L + l];
        uint4 v2 = Zq[(size_t)j4.z * L + l];
        uint4 v3 = Zq[(size_t)j4.w * L + l];
        add8(a, v0);
        add8(a, v1);
        add8(a, v2);
        add8(a, v3);
    }
}

__device__ inline uint4 pack8s(const float (&a)[8], float d, const float* __restrict__ bias, int l) {
    float4 b0 = *(const float4*)&bias[8 * l];
    float4 b1 = *(const float4*)&bias[8 * l + 4];
    float r0 = fmaxf(a[0] * d + b0.x, 0.f), r1 = fmaxf(a[1] * d + b0.y, 0.f);
    float r2 = fmaxf(a[2] * d + b0.z, 0.f), r3 = fmaxf(a[3] * d + b0.w, 0.f);
    float r4 = fmaxf(a[4] * d + b1.x, 0.f), r5 = fmaxf(a[5] * d + b1.y, 0.f);
    float r6 = fmaxf(a[6] * d + b1.z, 0.f), r7 = fmaxf(a[7] * d + b1.w, 0.f);
    uint4 o;
    o.x = ((uint32_t)f32_to_bf16(r1) << 16) | (uint32_t)f32_to_bf16(r0);
    o.y = ((uint32_t)f32_to_bf16(r3) << 16) | (uint32_t)f32_to_bf16(r2);
    o.z = ((uint32_t)f32_to_bf16(r5) << 16) | (uint32_t)f32_to_bf16(r4);
    o.w = ((uint32_t)f32_to_bf16(r7) << 16) | (uint32_t)f32_to_bf16(r6);
    return o;
}

// ---------------- fused agg + GEMM per 64-node tile (bf16 path) ----------------

template <int FIN, int FOUT>
__global__ __launch_bounds__(256) void k_aggmm(const ushort* __restrict__ Zin,
                                               const float* __restrict__ bias,
                                               const int* __restrict__ cnt,
                                               const int* __restrict__ bucket,
                                               const float* __restrict__ dis,
                                               const ushort* __restrict__ Wp,
                                               ushort* __restrict__ Zout, int n) {
    constexpr int L = FIN / 8;
    constexpr int GROUPS = 256 / L;
    constexpr int PASSES = 64 / GROUPS;
    __shared__ ushort tileA[64][FIN + 8];
    int node0 = blockIdx.x * 64;

    {
        int l = threadIdx.x & (L - 1);
        int g = threadIdx.x / L;
#pragma unroll
        for (int pass = 0; pass < PASSES; ++pass) {
            int local = pass * GROUPS + g;
            int i = node0 + local;
            if (i < n) {
                float a[8] = {0.f, 0.f, 0.f, 0.f, 0.f, 0.f, 0.f, 0.f};
                int degp = (cnt[i] + 3) & ~3;
                agg_sum<L>(a, (const uint4*)Zin, bucket + (size_t)i * CAP, degp, l, i);
                *(uint4*)&tileA[local][l * 8] = pack8s(a, dis[i], bias, l);
            }
        }
    }
    __syncthreads();

    constexpr int KS = FIN / 32;
    constexpr int FT = FOUT / 16;
    int wid = threadIdx.x >> 6;
    int lane = threadIdx.x & 63;
    int m = lane & 15;
    int quad = lane >> 4;
    int tbase = wid * 16;
    bf16x8 a[KS];
#pragma unroll
    for (int s = 0; s < KS; ++s)
        a[s] = *(const bf16x8*)&tileA[tbase + m][s * 32 + quad * 8];
    float dsc[4];
#pragma unroll
    for (int r = 0; r < 4; ++r) {
        int node = node0 + tbase + quad * 4 + r;
        dsc[r] = (node < n) ? dis[node] : 0.f;
    }
    const bf16x8* bp = (const bf16x8*)Wp;
#pragma unroll
    for (int t = 0; t < FT; ++t) {
        f32x4 acc = {0.f, 0.f, 0.f, 0.f};
#pragma unroll
        for (int s = 0; s < KS; ++s)
            acc = __builtin_amdgcn_mfma_f32_16x16x32_bf16(a[s], bp[(t * KS + s) * 64 + lane], acc, 0, 0, 0);
        int feat = t * 16 + m;
#pragma unroll
        for (int r = 0; r < 4; ++r) {
            int node = node0 + tbase + quad * 4 + r;
            if (node < n) Zout[(size_t)node * FOUT + feat] = f32_to_bf16(acc[r] * dsc[r]);
        }
    }
}

// Layer-4 agg fused with 64->1 W5 projection; 8 lanes/node.
__global__ __launch_bounds__(256) void k_agg64z(const ushort* __restrict__ Z,
                                                const float* __restrict__ bias,
                                                const float* __restrict__ W5,
                                                const int* __restrict__ cnt,
                                                const int* __restrict__ bucket,
                                                const float* __restrict__ dis,
                                                float* __restrict__ zbuf, int n) {
    int l = threadIdx.x & 7;
    int i = blockIdx.x * 32 + (threadIdx.x >> 3);
    if (i >= n) return;
    float a[8] = {0.f, 0.f, 0.f, 0.f, 0.f, 0.f, 0.f, 0.f};
    int degp = (cnt[i] + 3) & ~3;
    agg_sum<8>(a, (const uint4*)Z, bucket + (size_t)i * CAP, degp, l, i);
    float d = dis[i];
    float4 b0 = *(const float4*)&bias[8 * l];
    float4 b1 = *(const float4*)&bias[8 * l + 4];
    float4 w0 = *(const float4*)&W5[8 * l];
    float4 w1 = *(const float4*)&W5[8 * l + 4];
    float p = fmaxf(a[0] * d + b0.x, 0.f) * w0.x + fmaxf(a[1] * d + b0.y, 0.f) * w0.y +
              fmaxf(a[2] * d + b0.z, 0.f) * w0.z + fmaxf(a[3] * d + b0.w, 0.f) * w0.w +
              fmaxf(a[4] * d + b1.x, 0.f) * w1.x + fmaxf(a[5] * d + b1.y, 0.f) * w1.y +
              fmaxf(a[6] * d + b1.z, 0.f) * w1.z + fmaxf(a[7] * d + b1.w, 0.f) * w1.w;
#pragma unroll
    for (int off = 4; off; off >>= 1) p += __shfl_xor(p, off, 64);
    if (l == 0) zbuf[i] = d * p;
}

// final: out_i = dis_i * (sum zbuf_j + zbuf_i) + b5   (padded, no remainder)
__global__ void k_agg1(const float* __restrict__ zbuf, const float* __restrict__ b5,
                       const int* __restrict__ cnt, const int* __restrict__ bucket,
                       const float* __restrict__ dis, float* __restrict__ out, int n) {
    int i = blockIdx.x * NB + threadIdx.x;
    if (i >= n) return;
    float acc = zbuf[i];
    int degp = (cnt[i] + 3) & ~3;
    const int* bk = bucket + (size_t)i * CAP;
    for (int e = 0; e < degp; e += 4) {
        int4 j4 = *(const int4*)(bk + e);
        acc += zbuf[j4.x] + zbuf[j4.y] + zbuf[j4.z] + zbuf[j4.w];
    }
    out[i] = dis[i] * acc + b5[0];
}

// ---------------- launch ----------------

static inline size_t align_up(size_t x) { return (x + 255) & ~(size_t)255; }

extern "C" void kernel_launch(void* const* d_in, const int* in_sizes, int n_in,
                              void* d_out, int out_size, void* d_ws, size_t ws_size,
                              hipStream_t stream) {
    const int n = in_sizes[0] / 3;   // 100000
    const int e = in_sizes[1] / 2;   // 600000

    const float* x   = (const float*)d_in[0];
    const int*   ei  = (const int*)d_in[1];
    const int*   row = ei;       // sources
    const int*   col = ei + e;   // targets
    const float* W1 = (const float*)d_in[2];  const float* b1 = (const float*)d_in[3];
    const float* W2 = (const float*)d_in[4];  const float* b2 = (const float*)d_in[5];
    const float* W3 = (const float*)d_in[6];  const float* b3 = (const float*)d_in[7];
    const float* W4 = (const float*)d_in[8];  const float* b4 = (const float*)d_in[9];
    const float* W5 = (const float*)d_in[10]; const float* b5 = (const float*)d_in[11];
    float* out = (float*)d_out;

    char* base = (char*)d_ws;
    size_t off = 0;
    auto alloc = [&](size_t bytes) { char* p = base + off; off = align_up(off + bytes); return p; };
    int*     cursor = (int*)alloc((size_t)n * 4);               // becomes degree
    float*   dis    = (float*)alloc((size_t)n * 4);
    float4*  xs4    = (float4*)alloc((size_t)(n + 1) * 16);
    int*     bucket = (int*)alloc((size_t)n * CAP * 4);         // 25.6 MB
    uint8_t* G      = (uint8_t*)alloc((size_t)(n + 1) * 128);   // u8, 128-wide + zero row
    float*   sG     = (float*)alloc((size_t)(n + 1) * 4);       // per-row scales
    ushort*  A      = (ushort*)alloc((size_t)(n + 1) * 64 * 2); // bf16, 64-wide + zero row
    ushort*  C      = (ushort*)alloc((size_t)(n + 1) * 64 * 2); // bf16, 64-wide + zero row
    float*   zbuf   = (float*)alloc((size_t)(n + 1) * 4);
    ushort*  Wp2    = (ushort*)alloc(128 * 128 * 2);
    ushort*  Wp3    = (ushort*)alloc(128 * 64 * 2);
    ushort*  Wp4    = (ushort*)alloc(64 * 64 * 2);
    (void)ws_size;

    const int gn = ceil_div(n, NB);        // 391
    const int pack_blocks = ceil_div(16384 + 8192 + 4096, NB);  // 112

    // bucket CSR build (+ padding & zero rows in k_dis)
    k_init<<<gn + pack_blocks, NB, 0, stream>>>(cursor, n, gn, W2, W3, W4, Wp2, Wp3, Wp4);
    k_fillb<<<ceil_div(ceil_div(e, 8), NB), NB, 0, stream>>>(row, col, e, cursor, bucket);
    k_dis<<<gn, NB, 0, stream>>>(cursor, x, dis, xs4, bucket, G, sG, A, C, zbuf, n);

    // Layer 1: G = dis (.) relu(agg3(x)@W1 + b1), u8 row-scaled
    k_l1q<<<ceil_div(n, 64), 256, 0, stream>>>(xs4, cursor, bucket, dis, W1, b1, G, sG, n);

    // Layer 2 agg (u8) + W2 GEMM + relu + W3 GEMM: A = dis (.) (relu(dis*agg(G)@W2+b2) @ W3)
    k_aggu8<<<ceil_div(n, 64), 256, 0, stream>>>(G, sG, b2, cursor, bucket, dis, Wp2, Wp3, A, n);

    // Layer 3 agg + Layer 4 GEMM (fused): C = dis (.) (relu-agg(A,b3) @ W4)
    k_aggmm<64, 64><<<ceil_div(n, 64), 256, 0, stream>>>(A, b3, cursor, bucket, dis, Wp4, C, n);

    // Layer 4 agg + W5 projection
    k_agg64z<<<ceil_div(n, 32), 256, 0, stream>>>(C, b4, W5, cursor, bucket, dis, zbuf, n);

    // Layer 5
    k_agg1<<<gn, NB, 0, stream>>>(zbuf, b5, cursor, bucket, dis, out, n);
}